// Round 7
// baseline (236.290 us; speedup 1.0000x reference)
//
#include <hip/hip_runtime.h>

// Window attention, fused fp16-MFMA, 2 waves split one (b,h) by token halves.
// prep_w16: qkv_w f32 -> fp16 (ws). prep_cmb: cmb[w][h][e] = rpb[rpi[e]*4+h] + mask[w][e] (ws).
// attn_fused: block = one (window b, head h), 2 waves; wave wv owns tokens [32wv, 32wv+31]:
//   computes q/k/v for its tokens (48 MFMAs, B=w16 direct global), stages to shared LDS,
//   QK^T (8) -> softmax (no max-sub, deferred 1/sum) -> PV (8) -> aout fp16.
// proj_gemm_mfma: out = aout @ proj_w^T + proj_b (f32), unchanged (at HBM floor).
#define B_WIN 4096
#define NTOK 49
#define DIMC 128
#define HEADS 4
#define HD 32
#define NWIN 64
#define MTOT (B_WIN * 49) /* 200704 */
#define SCALE_Q 0.17677669529663687f /* 32^-0.5 */

typedef _Float16 half8 __attribute__((ext_vector_type(8)));
typedef float f32x4 __attribute__((ext_vector_type(4)));
typedef unsigned short ushortv8 __attribute__((ext_vector_type(8)));

__device__ __forceinline__ unsigned short f2h(float f) {
    _Float16 h = (_Float16)f; // RNE
    return __builtin_bit_cast(unsigned short, h);
}

#define LDP 136 /* fp16 LDS row pitch for proj GEMM */

// ---------------- prep1: qkv_w f32 -> fp16 ----------------
__global__ __launch_bounds__(256) void prep_w16(
    const float* __restrict__ w, unsigned short* __restrict__ w16)
{
    int i = blockIdx.x * 256 + threadIdx.x;
    if (i < 384 * 128) w16[i] = f2h(w[i]);
}

// ---------------- prep2: combined bias+mask table cmb[w][h][e] ----------------
__global__ __launch_bounds__(256) void prep_cmb(
    const float* __restrict__ rpb, const int* __restrict__ rpi,
    const float* __restrict__ mask, float* __restrict__ cmb)
{
    int idx = blockIdx.x * 256 + threadIdx.x; // 64*4*2401 = 614656
    if (idx < NWIN * HEADS * 2401) {
        int e = idx % 2401;
        int wh = idx / 2401;
        int h = wh & 3, w = wh >> 2;
        cmb[idx] = rpb[rpi[e] * 4 + h] + mask[w * 2401 + e];
    }
}

// ---------------- fused qkv-gemm + attention ----------------
// LDS (14848 B / block): Qs[64][40] | Ks[64][40] | Vt[32][72]; Ps[64][72] overlaps Qs+Ks.
// -> 11 blocks/CU (LDS-capped), 22 waves/CU.
__global__ __launch_bounds__(128, 5) void attn_fused(
    const float* __restrict__ x, const unsigned short* __restrict__ w16,
    const float* __restrict__ qkv_b, const float* __restrict__ cmb,
    unsigned short* __restrict__ aout)
{
    __shared__ __align__(16) char smem[14848];
    const int t = threadIdx.x, wv = t >> 6, lane = t & 63;
    const int c = lane & 15, g = lane >> 4;
    const int bid = blockIdx.x;
    const int b = bid >> 2, h = bid & 3;

    unsigned short* Qs = (unsigned short*)smem;            // [64][40]
    unsigned short* Ks = (unsigned short*)(smem + 5120);   // [64][40]
    unsigned short* Vt = (unsigned short*)(smem + 10240);  // [32][72]
    unsigned short* Ps = (unsigned short*)smem;            // [64][72], overlaps Qs+Ks

    // ---- Vt zero-fill (token cols >=49 must be finite 0 for PV) ----
    {
        uint4 z; z.x = z.y = z.z = z.w = 0u;
#pragma unroll
        for (int it = 0; it < 3; ++it) {
            int idx = it * 128 + t;
            if (idx < 288) *(uint4*)(smem + 10240 + idx * 16) = z;
        }
    }
    __syncthreads(); // #1: zero-fill vs V epilogue writes are cross-wave

    // ---- A-frags: this wave's 2 token tiles of x, f32 -> fp16 in-reg ----
    half8 af[2][4];
#pragma unroll
    for (int mt = 0; mt < 2; ++mt) {
        int rowg = b * 49 + 16 * (2 * wv + mt) + c;
        rowg = min(rowg, MTOT - 1); // clamp at buffer tail (garbage masked later)
        const float* xr = x + (size_t)rowg * 128;
#pragma unroll
        for (int ks = 0; ks < 4; ++ks) {
            float4 lo = *(const float4*)(xr + 32 * ks + 8 * g);
            float4 hi = *(const float4*)(xr + 32 * ks + 8 * g + 4);
            half8 v;
            v[0] = (_Float16)lo.x; v[1] = (_Float16)lo.y;
            v[2] = (_Float16)lo.z; v[3] = (_Float16)lo.w;
            v[4] = (_Float16)hi.x; v[5] = (_Float16)hi.y;
            v[6] = (_Float16)hi.z; v[7] = (_Float16)hi.w;
            af[mt][ks] = v;
        }
    }

    // ---- qkv gemm for this wave's tokens: 6 tiles (q0,q1,k0,k1,v0,v1) ----
#pragma unroll
    for (int jt = 0; jt < 6; ++jt) {
        const int sec = jt >> 1;        // 0=q, 1=k, 2=v
        const int dt16 = (jt & 1) * 16; // d offset within head
        const int tb = sec * 128 + h * 32 + dt16;
        half8 bf[4];
#pragma unroll
        for (int ks = 0; ks < 4; ++ks)
            bf[ks] = *(const half8*)(w16 + (size_t)(tb + c) * 128 + 32 * ks + 8 * g);
        f32x4 acc[2];
#pragma unroll
        for (int mt = 0; mt < 2; ++mt) acc[mt] = (f32x4){0.f, 0.f, 0.f, 0.f};
#pragma unroll
        for (int ks = 0; ks < 4; ++ks)
#pragma unroll
            for (int mt = 0; mt < 2; ++mt)
                acc[mt] = __builtin_amdgcn_mfma_f32_16x16x32_f16(af[mt][ks], bf[ks], acc[mt], 0, 0, 0);
        const float bv = qkv_b[tb + c];
        const int d = dt16 + c;
#pragma unroll
        for (int mt = 0; mt < 2; ++mt) {
#pragma unroll
            for (int r = 0; r < 4; ++r) {
                const int m = 16 * (2 * wv + mt) + 4 * g + r;
                if (m < 49) {
                    float val = acc[mt][r] + bv;
                    if (sec == 0)      Qs[m * 40 + d] = f2h(val * SCALE_Q);
                    else if (sec == 1) Ks[m * 40 + d] = f2h(val);
                    else               Vt[d * 72 + m] = f2h(val);
                }
            }
        }
    }
    __syncthreads(); // #2: K/V staged by the other wave before frag reads

    // ---- QK^T frags (rows >=49 garbage-but-masked) ----
    half8 qf[2], kf[4];
#pragma unroll
    for (int mt = 0; mt < 2; ++mt)
        qf[mt] = *(const half8*)(Qs + (16 * (2 * wv + mt) + c) * 40 + 8 * g);
#pragma unroll
    for (int nt = 0; nt < 4; ++nt)
        kf[nt] = *(const half8*)(Ks + (16 * nt + c) * 40 + 8 * g);

    __syncthreads(); // #3: Ps writes alias Qs/Ks which the other wave just read

    // ---- QK^T (8 MFMAs) ----
    f32x4 s[2][4];
#pragma unroll
    for (int mt = 0; mt < 2; ++mt)
#pragma unroll
        for (int nt = 0; nt < 4; ++nt) {
            s[mt][nt] = (f32x4){0.f, 0.f, 0.f, 0.f};
            s[mt][nt] = __builtin_amdgcn_mfma_f32_16x16x32_f16(qf[mt], kf[nt], s[mt][nt], 0, 0, 0);
        }

    // ---- softmax: +cmb, exp (no max-sub), 16-lane row-sum, P(unnorm) -> Ps ----
    const float* crow = cmb + (size_t)(((b & (NWIN - 1)) << 2) | h) * 2401;
    float invs[2][4];
#pragma unroll
    for (int mt = 0; mt < 2; ++mt) {
#pragma unroll
        for (int r = 0; r < 4; ++r) {
            const int m = 16 * (2 * wv + mt) + 4 * g + r;
            float sum = 0.f;
#pragma unroll
            for (int nt = 0; nt < 4; ++nt) {
                const int n = 16 * nt + c;
                float p = 0.f;
                if (m < 49 && n < 49) p = __expf(s[mt][nt][r] + crow[m * 49 + n]);
                s[mt][nt][r] = p;
                sum += p;
            }
#pragma unroll
            for (int sh = 1; sh < 16; sh <<= 1) sum += __shfl_xor(sum, sh, 64);
            invs[mt][r] = 1.0f / sum; // inf for pad rows; never stored
#pragma unroll
            for (int nt = 0; nt < 4; ++nt)
                Ps[m * 72 + 16 * nt + c] = f2h(s[mt][nt][r]);
        }
    }

    // ---- PV (8 MFMAs); this wave reads only its own Ps rows (in-order), Vt stable ----
    f32x4 o[2][2];
#pragma unroll
    for (int mt = 0; mt < 2; ++mt)
#pragma unroll
        for (int dt = 0; dt < 2; ++dt) o[mt][dt] = (f32x4){0.f, 0.f, 0.f, 0.f};

#pragma unroll
    for (int ks = 0; ks < 2; ++ks) {
        half8 pf[2], vf[2];
#pragma unroll
        for (int mt = 0; mt < 2; ++mt)
            pf[mt] = *(const half8*)(Ps + (16 * (2 * wv + mt) + c) * 72 + 8 * g + 32 * ks);
#pragma unroll
        for (int dt = 0; dt < 2; ++dt)
            vf[dt] = *(const half8*)(Vt + (16 * dt + c) * 72 + 8 * g + 32 * ks);
#pragma unroll
        for (int mt = 0; mt < 2; ++mt)
#pragma unroll
            for (int dt = 0; dt < 2; ++dt)
                o[mt][dt] = __builtin_amdgcn_mfma_f32_16x16x32_f16(pf[mt], vf[dt], o[mt][dt], 0, 0, 0);
    }

    // ---- normalize at store: aout (b, n, h*32+d) fp16 ----
    unsigned short* orow = aout + (size_t)b * NTOK * DIMC + h * HD;
#pragma unroll
    for (int mt = 0; mt < 2; ++mt) {
#pragma unroll
        for (int r = 0; r < 4; ++r) {
            const int m = 16 * (2 * wv + mt) + 4 * g + r;
            if (m < 49) {
                const float iv = invs[mt][r];
#pragma unroll
                for (int dt = 0; dt < 2; ++dt)
                    orow[m * DIMC + 16 * dt + c] = f2h(o[mt][dt][r] * iv);
            }
        }
    }
}

// ---------------- GEMM2: out = attn_out @ proj_w^T + proj_b (f32 out) — at HBM floor ----------------
__global__ __launch_bounds__(256) void proj_gemm_mfma(
    const unsigned short* __restrict__ a, const float* __restrict__ w,
    const float* __restrict__ bias, float* __restrict__ out)
{
    __shared__ unsigned short As[128 * LDP];
    __shared__ unsigned short Bs[128 * LDP];
    const int t = threadIdx.x, lane = t & 63, wid = t >> 6;
    const int c = lane & 15, g = lane >> 4;
    const int m0 = blockIdx.x * 128;

#pragma unroll
    for (int i = 0; i < 8; ++i) {
        int idx = i * 256 + t;
        int row = idx >> 4, c8 = (idx & 15) * 8;
        *(uint4*)&As[row * LDP + c8] = *(const uint4*)(a + (size_t)(m0 + row) * 128 + c8);
    }
#pragma unroll
    for (int i = 0; i < 8; ++i) {
        int idx = i * 256 + t;
        int row = idx >> 4, c8 = (idx & 15) * 8;
        const float* sb = w + (size_t)row * 128 + c8;
        float4 b0 = *(const float4*)sb, b1 = *(const float4*)(sb + 4);
        ushortv8 pb = { f2h(b0.x), f2h(b0.y), f2h(b0.z), f2h(b0.w),
                        f2h(b1.x), f2h(b1.y), f2h(b1.z), f2h(b1.w) };
        *(ushortv8*)&Bs[row * LDP + c8] = pb;
    }
    __syncthreads();

    const int wr = wid >> 1, wc = wid & 1;
    f32x4 acc[4][4];
#pragma unroll
    for (int mt = 0; mt < 4; ++mt)
#pragma unroll
        for (int nt = 0; nt < 4; ++nt) acc[mt][nt] = (f32x4){0.f, 0.f, 0.f, 0.f};

#pragma unroll
    for (int ks = 0; ks < 4; ++ks) {
        half8 af[4], bf[4];
#pragma unroll
        for (int mt = 0; mt < 4; ++mt)
            af[mt] = *(const half8*)&As[(64 * wr + 16 * mt + c) * LDP + 32 * ks + 8 * g];
#pragma unroll
        for (int nt = 0; nt < 4; ++nt)
            bf[nt] = *(const half8*)&Bs[(64 * wc + 16 * nt + c) * LDP + 32 * ks + 8 * g];
#pragma unroll
        for (int mt = 0; mt < 4; ++mt)
#pragma unroll
            for (int nt = 0; nt < 4; ++nt)
                acc[mt][nt] = __builtin_amdgcn_mfma_f32_16x16x32_f16(af[mt], bf[nt], acc[mt][nt], 0, 0, 0);
    }

#pragma unroll
    for (int nt = 0; nt < 4; ++nt) {
        const int col = 64 * wc + 16 * nt + c;
        const float bv = bias[col];
#pragma unroll
        for (int mt = 0; mt < 4; ++mt) {
#pragma unroll
            for (int r = 0; r < 4; ++r) {
                int m = m0 + 64 * wr + 16 * mt + 4 * g + r;
                out[(size_t)m * 128 + col] = acc[mt][nt][r] + bv;
            }
        }
    }
}

extern "C" void kernel_launch(void* const* d_in, const int* in_sizes, int n_in,
                              void* d_out, int out_size, void* d_ws, size_t ws_size,
                              hipStream_t stream) {
    const float* x      = (const float*)d_in[0];
    const float* mask   = (const float*)d_in[1];
    const float* qkv_w  = (const float*)d_in[2];
    const float* qkv_b  = (const float*)d_in[3];
    const float* proj_w = (const float*)d_in[4];
    const float* proj_b = (const float*)d_in[5];
    const float* rpb    = (const float*)d_in[6];
    const int*   rpi    = (const int*)d_in[7];
    float* out = (float*)d_out;

    unsigned short* ab  = (unsigned short*)d_ws;          // 25,690,112 u16 (49 MB)
    unsigned short* w16 = ab + (size_t)MTOT * DIMC;       // 49,152 u16
    float* cmb = (float*)(w16 + 49152);                   // 614,656 f32 (2.5 MB)

    prep_w16<<<dim3(192), 256, 0, stream>>>(qkv_w, w16);
    prep_cmb<<<dim3(2401), 256, 0, stream>>>(rpb, rpi, mask, cmb);
    attn_fused<<<dim3(B_WIN * HEADS), 128, 0, stream>>>(x, w16, qkv_b, cmb, ab);
    proj_gemm_mfma<<<dim3(MTOT / 128), 256, 0, stream>>>(ab, proj_w, proj_b, out);
}

// Round 8
// 210.275 us; speedup vs baseline: 1.1237x; 1.1237x over previous
//
#include <hip/hip_runtime.h>

// Window attention, fused fp16-MFMA. Block = 1 window (4 waves = 4 heads), no barriers.
// prep_w16: qkv_w f32->fp16. prep_cmb: cmb[w][h][e] = rpb[rpi[e]*4+h] + mask[w][e].
// attn_fused: per wave: qkv gemm (A=x global+cvt, B=w16 global; mt-pair staged) ->
//   Q,K -> wave-private LDS; V packed in registers; QK^T (2 m-half passes) -> softmax
//   (no max-sub, normalized into Ps) -> PV with V B-frags built via shfl -> aout fp16.
// proj_gemm_mfma: out = aout @ proj_w^T + proj_b (f32), at HBM floor.
#define B_WIN 4096
#define NTOK 49
#define DIMC 128
#define HEADS 4
#define HD 32
#define NWIN 64
#define MTOT (B_WIN * 49) /* 200704 */
#define SCALE_Q 0.17677669529663687f /* 32^-0.5 */

typedef _Float16 half8 __attribute__((ext_vector_type(8)));
typedef float f32x4 __attribute__((ext_vector_type(4)));
typedef unsigned short ushortv8 __attribute__((ext_vector_type(8)));

__device__ __forceinline__ unsigned short f2h(float f) {
    _Float16 h = (_Float16)f; // RNE
    return __builtin_bit_cast(unsigned short, h);
}
__device__ __forceinline__ unsigned packh2(float a, float b) {
    return (unsigned)f2h(a) | ((unsigned)f2h(b) << 16);
}

#define LDP 136 /* fp16 LDS row pitch for proj GEMM */

// ---------------- prep1: qkv_w f32 -> fp16 ----------------
__global__ __launch_bounds__(256) void prep_w16(
    const float* __restrict__ w, unsigned short* __restrict__ w16)
{
    int i = blockIdx.x * 256 + threadIdx.x;
    if (i < 384 * 128) w16[i] = f2h(w[i]);
}

// ---------------- prep2: combined bias+mask table cmb[w][h][e] ----------------
__global__ __launch_bounds__(256) void prep_cmb(
    const float* __restrict__ rpb, const int* __restrict__ rpi,
    const float* __restrict__ mask, float* __restrict__ cmb)
{
    int idx = blockIdx.x * 256 + threadIdx.x; // 64*4*2401 = 614656
    if (idx < NWIN * HEADS * 2401) {
        int e = idx % 2401;
        int wh = idx / 2401;
        int h = wh & 3, w = wh >> 2;
        cmb[idx] = rpb[rpi[e] * 4 + h] + mask[w * 2401 + e];
    }
}

// ---------------- fused qkv-gemm + attention ----------------
// Per-wave LDS 10240 B: Qs[64][40] | Ks[64][40]; Ps[64][72] (9216 B) overlays Qs+Ks.
// 4 waves x 10240 = 40960 B/block -> exactly 4 blocks/CU (160 KiB), 16 waves/CU.
__global__ __launch_bounds__(256, 4) void attn_fused(
    const float* __restrict__ x, const unsigned short* __restrict__ w16,
    const float* __restrict__ qkv_b, const float* __restrict__ cmb,
    unsigned short* __restrict__ aout)
{
    __shared__ __align__(16) char smem[4 * 10240];
    const int t = threadIdx.x, wv = t >> 6, lane = t & 63;
    const int c = lane & 15, g = lane >> 4;
    const int gl = g & 1, gh = g >> 1;
    const int b = blockIdx.x, h = wv;

    unsigned short* Qs = (unsigned short*)(smem + wv * 10240); // [64][40]
    unsigned short* Ks = Qs + 64 * 40;                          // [64][40]
    unsigned short* Ps = Qs;                                    // [64][72] overlay

    // ---- qkv gemm, mt-pairs to cap VGPR. V -> registers (C-layout packed). ----
    unsigned vlo[4][2], vhi[4][2]; // [mt][dhalf]: {h(r0)|h(r1)<<16}, {h(r2)|h(r3)<<16}
#pragma unroll
    for (int mh = 0; mh < 2; ++mh) {
        half8 af[2][4];
#pragma unroll
        for (int i = 0; i < 2; ++i) {
            int rowg = b * 49 + 16 * (2 * mh + i) + c;
            rowg = min(rowg, MTOT - 1); // clamp: tail garbage is finite & masked
            const float* xr = x + (size_t)rowg * 128;
#pragma unroll
            for (int ks = 0; ks < 4; ++ks) {
                float4 lo = *(const float4*)(xr + 32 * ks + 8 * g);
                float4 hi = *(const float4*)(xr + 32 * ks + 8 * g + 4);
                half8 v;
                v[0] = (_Float16)lo.x; v[1] = (_Float16)lo.y;
                v[2] = (_Float16)lo.z; v[3] = (_Float16)lo.w;
                v[4] = (_Float16)hi.x; v[5] = (_Float16)hi.y;
                v[6] = (_Float16)hi.z; v[7] = (_Float16)hi.w;
                af[i][ks] = v;
            }
        }
#pragma unroll
        for (int jt = 0; jt < 6; ++jt) {
            const int sec = jt >> 1, dhalf = jt & 1;
            const int tb = sec * 128 + h * 32 + dhalf * 16;
            half8 bf[4];
#pragma unroll
            for (int ks = 0; ks < 4; ++ks)
                bf[ks] = *(const half8*)(w16 + (size_t)(tb + c) * 128 + 32 * ks + 8 * g);
            f32x4 acc[2];
            acc[0] = (f32x4){0.f, 0.f, 0.f, 0.f};
            acc[1] = (f32x4){0.f, 0.f, 0.f, 0.f};
#pragma unroll
            for (int ks = 0; ks < 4; ++ks)
#pragma unroll
                for (int i = 0; i < 2; ++i)
                    acc[i] = __builtin_amdgcn_mfma_f32_16x16x32_f16(af[i][ks], bf[ks], acc[i], 0, 0, 0);
            const float bv = qkv_b[tb + c];
#pragma unroll
            for (int i = 0; i < 2; ++i) {
                const int mt = 2 * mh + i;
                if (sec == 2) {
                    vlo[mt][dhalf] = packh2(acc[i][0] + bv, acc[i][1] + bv);
                    vhi[mt][dhalf] = packh2(acc[i][2] + bv, acc[i][3] + bv);
                } else {
                    unsigned short* dstS = (sec == 0) ? Qs : Ks;
                    const float scl = (sec == 0) ? SCALE_Q : 1.0f;
                    const int d = dhalf * 16 + c;
#pragma unroll
                    for (int r = 0; r < 4; ++r) {
                        const int m = 16 * mt + 4 * g + r;
                        if (m < 49) dstS[m * 40 + d] = f2h((acc[i][r] + bv) * scl);
                    }
                }
            }
        }
    }

    // ---- hoist Q/K frags BEFORE Ps overlay clobbers Qs/Ks ----
    half8 qf[4], kf[4];
#pragma unroll
    for (int mt = 0; mt < 4; ++mt) qf[mt] = *(const half8*)(Qs + (16 * mt + c) * 40 + 8 * g);
#pragma unroll
    for (int nt = 0; nt < 4; ++nt) kf[nt] = *(const half8*)(Ks + (16 * nt + c) * 40 + 8 * g);

    // ---- QK^T + softmax in two m-half passes (caps VGPR) ----
    const float* crow = cmb + (size_t)(((b & (NWIN - 1)) << 2) | h) * 2401;
#pragma unroll
    for (int mh = 0; mh < 2; ++mh) {
        f32x4 s2[2][4];
#pragma unroll
        for (int i = 0; i < 2; ++i)
#pragma unroll
            for (int nt = 0; nt < 4; ++nt) {
                s2[i][nt] = (f32x4){0.f, 0.f, 0.f, 0.f};
                s2[i][nt] = __builtin_amdgcn_mfma_f32_16x16x32_f16(qf[2 * mh + i], kf[nt], s2[i][nt], 0, 0, 0);
            }
#pragma unroll
        for (int i = 0; i < 2; ++i) {
#pragma unroll
            for (int r = 0; r < 4; ++r) {
                const int m = 16 * (2 * mh + i) + 4 * g + r;
                float sum = 0.f;
#pragma unroll
                for (int nt = 0; nt < 4; ++nt) {
                    const int n = 16 * nt + c;
                    float p = 0.f;
                    if (m < 49 && n < 49) p = __expf(s2[i][nt][r] + crow[m * 49 + n]);
                    s2[i][nt][r] = p;
                    sum += p;
                }
#pragma unroll
                for (int sh = 1; sh < 16; sh <<= 1) sum += __shfl_xor(sum, sh, 64);
                const float iv = (m < 49) ? 1.0f / sum : 0.0f;
#pragma unroll
                for (int nt = 0; nt < 4; ++nt)
                    Ps[m * 72 + 16 * nt + c] = f2h(s2[i][nt][r] * iv);
            }
        }
    }

    // ---- PV: vf built from register V via shfl (no LDS for V) ----
    // target lane (c,g), k-slice ks, d-tile dt: vf[j] = v[32ks+8g+j][16dt+c];
    // source lane (c, 2*gl + j/4) holds it in tile mt'=2ks+gh, elem r=j%4.
    f32x4 o[4][2];
#pragma unroll
    for (int mt = 0; mt < 4; ++mt)
#pragma unroll
        for (int dt = 0; dt < 2; ++dt) o[mt][dt] = (f32x4){0.f, 0.f, 0.f, 0.f};

    const int s0 = c + 32 * gl, s1 = s0 + 16;
#pragma unroll
    for (int ks = 0; ks < 2; ++ks) {
        half8 vf[2];
#pragma unroll
        for (int dt = 0; dt < 2; ++dt) {
            unsigned a0 = __shfl(vlo[2 * ks][dt], s0), a1 = __shfl(vlo[2 * ks + 1][dt], s0);
            unsigned b0 = __shfl(vhi[2 * ks][dt], s0), b1 = __shfl(vhi[2 * ks + 1][dt], s0);
            unsigned c0 = __shfl(vlo[2 * ks][dt], s1), c1 = __shfl(vlo[2 * ks + 1][dt], s1);
            unsigned d0 = __shfl(vhi[2 * ks][dt], s1), d1 = __shfl(vhi[2 * ks + 1][dt], s1);
            uint4 vv;
            vv.x = gh ? a1 : a0; vv.y = gh ? b1 : b0;
            vv.z = gh ? c1 : c0; vv.w = gh ? d1 : d0;
            vf[dt] = __builtin_bit_cast(half8, vv);
        }
#pragma unroll
        for (int mt = 0; mt < 4; ++mt) {
            half8 pf = *(const half8*)(Ps + (16 * mt + c) * 72 + 8 * g + 32 * ks);
#pragma unroll
            for (int dt = 0; dt < 2; ++dt)
                o[mt][dt] = __builtin_amdgcn_mfma_f32_16x16x32_f16(pf, vf[dt], o[mt][dt], 0, 0, 0);
        }
    }

    // ---- store aout (b, n, h*32+d) fp16 (P pre-normalized) ----
    unsigned short* orow = aout + (size_t)b * NTOK * DIMC + h * HD;
#pragma unroll
    for (int mt = 0; mt < 4; ++mt) {
#pragma unroll
        for (int r = 0; r < 4; ++r) {
            const int m = 16 * mt + 4 * g + r;
            if (m < 49) {
#pragma unroll
                for (int dt = 0; dt < 2; ++dt)
                    orow[m * DIMC + 16 * dt + c] = f2h(o[mt][dt][r]);
            }
        }
    }
}

// ---------------- GEMM2: out = attn_out @ proj_w^T + proj_b (f32 out) — at HBM floor ----------------
__global__ __launch_bounds__(256) void proj_gemm_mfma(
    const unsigned short* __restrict__ a, const float* __restrict__ w,
    const float* __restrict__ bias, float* __restrict__ out)
{
    __shared__ unsigned short As[128 * LDP];
    __shared__ unsigned short Bs[128 * LDP];
    const int t = threadIdx.x, lane = t & 63, wid = t >> 6;
    const int c = lane & 15, g = lane >> 4;
    const int m0 = blockIdx.x * 128;

#pragma unroll
    for (int i = 0; i < 8; ++i) {
        int idx = i * 256 + t;
        int row = idx >> 4, c8 = (idx & 15) * 8;
        *(uint4*)&As[row * LDP + c8] = *(const uint4*)(a + (size_t)(m0 + row) * 128 + c8);
    }
#pragma unroll
    for (int i = 0; i < 8; ++i) {
        int idx = i * 256 + t;
        int row = idx >> 4, c8 = (idx & 15) * 8;
        const float* sb = w + (size_t)row * 128 + c8;
        float4 b0 = *(const float4*)sb, b1 = *(const float4*)(sb + 4);
        ushortv8 pb = { f2h(b0.x), f2h(b0.y), f2h(b0.z), f2h(b0.w),
                        f2h(b1.x), f2h(b1.y), f2h(b1.z), f2h(b1.w) };
        *(ushortv8*)&Bs[row * LDP + c8] = pb;
    }
    __syncthreads();

    const int wr = wid >> 1, wc = wid & 1;
    f32x4 acc[4][4];
#pragma unroll
    for (int mt = 0; mt < 4; ++mt)
#pragma unroll
        for (int nt = 0; nt < 4; ++nt) acc[mt][nt] = (f32x4){0.f, 0.f, 0.f, 0.f};

#pragma unroll
    for (int ks = 0; ks < 4; ++ks) {
        half8 af[4], bf[4];
#pragma unroll
        for (int mt = 0; mt < 4; ++mt)
            af[mt] = *(const half8*)&As[(64 * wr + 16 * mt + c) * LDP + 32 * ks + 8 * g];
#pragma unroll
        for (int nt = 0; nt < 4; ++nt)
            bf[nt] = *(const half8*)&Bs[(64 * wc + 16 * nt + c) * LDP + 32 * ks + 8 * g];
#pragma unroll
        for (int mt = 0; mt < 4; ++mt)
#pragma unroll
            for (int nt = 0; nt < 4; ++nt)
                acc[mt][nt] = __builtin_amdgcn_mfma_f32_16x16x32_f16(af[mt], bf[nt], acc[mt][nt], 0, 0, 0);
    }

#pragma unroll
    for (int nt = 0; nt < 4; ++nt) {
        const int col = 64 * wc + 16 * nt + c;
        const float bv = bias[col];
#pragma unroll
        for (int mt = 0; mt < 4; ++mt) {
#pragma unroll
            for (int r = 0; r < 4; ++r) {
                int m = m0 + 64 * wr + 16 * mt + 4 * g + r;
                out[(size_t)m * 128 + col] = acc[mt][nt][r] + bv;
            }
        }
    }
}

extern "C" void kernel_launch(void* const* d_in, const int* in_sizes, int n_in,
                              void* d_out, int out_size, void* d_ws, size_t ws_size,
                              hipStream_t stream) {
    const float* x      = (const float*)d_in[0];
    const float* mask   = (const float*)d_in[1];
    const float* qkv_w  = (const float*)d_in[2];
    const float* qkv_b  = (const float*)d_in[3];
    const float* proj_w = (const float*)d_in[4];
    const float* proj_b = (const float*)d_in[5];
    const float* rpb    = (const float*)d_in[6];
    const int*   rpi    = (const int*)d_in[7];
    float* out = (float*)d_out;

    unsigned short* ab  = (unsigned short*)d_ws;          // 25,690,112 u16 (49 MB)
    unsigned short* w16 = ab + (size_t)MTOT * DIMC;       // 49,152 u16
    float* cmb = (float*)(w16 + 49152);                   // 614,656 f32 (2.5 MB)

    prep_w16<<<dim3(192), 256, 0, stream>>>(qkv_w, w16);
    prep_cmb<<<dim3(2401), 256, 0, stream>>>(rpb, rpi, mask, cmb);
    attn_fused<<<dim3(B_WIN), 256, 0, stream>>>(x, w16, qkv_b, cmb, ab);
    proj_gemm_mfma<<<dim3(MTOT / 128), 256, 0, stream>>>(ab, proj_w, proj_b, out);
}

// Round 9
// 175.984 us; speedup vs baseline: 1.3427x; 1.1949x over previous
//
#include <hip/hip_runtime.h>

// Window attention, fused fp16-MFMA. Block = 1 window (4 waves = 4 heads), no barriers.
// prep_w16: qkv_w f32->fp16. prep_cmb: cmb[w][h][e] = rpb[rpi[e]*4+h] + mask[w][e].
// attn_fused: per wave: qkv gemm (A=x global+cvt hoisted, B=w16 global dbuf) ->
//   Q,K -> wave-private LDS; V in registers; QK^T -> single-pass softmax (no max-sub,
//   normalized into Ps) -> PV with V B-frags via shfl -> aout fp16.
// proj_gemm_mfma: out = aout @ proj_w^T + proj_b (f32), at HBM floor.
#define B_WIN 4096
#define NTOK 49
#define DIMC 128
#define HEADS 4
#define HD 32
#define NWIN 64
#define MTOT (B_WIN * 49) /* 200704 */
#define SCALE_Q 0.17677669529663687f /* 32^-0.5 */

typedef _Float16 half8 __attribute__((ext_vector_type(8)));
typedef float f32x4 __attribute__((ext_vector_type(4)));
typedef unsigned short ushortv8 __attribute__((ext_vector_type(8)));

__device__ __forceinline__ unsigned short f2h(float f) {
    _Float16 h = (_Float16)f; // RNE
    return __builtin_bit_cast(unsigned short, h);
}
__device__ __forceinline__ unsigned packh2(float a, float b) {
    return (unsigned)f2h(a) | ((unsigned)f2h(b) << 16);
}

#define LDP 136 /* fp16 LDS row pitch for proj GEMM */

// ---------------- prep1: qkv_w f32 -> fp16 ----------------
__global__ __launch_bounds__(256) void prep_w16(
    const float* __restrict__ w, unsigned short* __restrict__ w16)
{
    int i = blockIdx.x * 256 + threadIdx.x;
    if (i < 384 * 128) w16[i] = f2h(w[i]);
}

// ---------------- prep2: combined bias+mask table cmb[w][h][e] ----------------
__global__ __launch_bounds__(256) void prep_cmb(
    const float* __restrict__ rpb, const int* __restrict__ rpi,
    const float* __restrict__ mask, float* __restrict__ cmb)
{
    int idx = blockIdx.x * 256 + threadIdx.x; // 64*4*2401 = 614656
    if (idx < NWIN * HEADS * 2401) {
        int e = idx % 2401;
        int wh = idx / 2401;
        int h = wh & 3, w = wh >> 2;
        cmb[idx] = rpb[rpi[e] * 4 + h] + mask[w * 2401 + e];
    }
}

// ---------------- fused qkv-gemm + attention ----------------
// Per-wave LDS 10240 B: Qs[64][40] | Ks[64][40]; Ps[64][72] (9216 B) overlays Qs+Ks.
// 4 waves x 10240 = 40960 B/block. launch_bounds(256,3): VGPR cap ~170 (r8's 64 spilled).
__global__ __launch_bounds__(256, 3) void attn_fused(
    const float* __restrict__ x, const unsigned short* __restrict__ w16,
    const float* __restrict__ qkv_b, const float* __restrict__ cmb,
    unsigned short* __restrict__ aout)
{
    __shared__ __align__(16) char smem[4 * 10240];
    const int t = threadIdx.x, wv = t >> 6, lane = t & 63;
    const int c = lane & 15, g = lane >> 4;
    const int gl = g & 1, gh = g >> 1;
    const int b = blockIdx.x, h = wv;

    unsigned short* Qs = (unsigned short*)(smem + wv * 10240); // [64][40]
    unsigned short* Ks = Qs + 64 * 40;                          // [64][40]
    unsigned short* Ps = Qs;                                    // [64][72] overlay

    // ---- all x A-frags up front: one MLP burst, f32 -> fp16 in-reg ----
    half8 af[4][4];
#pragma unroll
    for (int mt = 0; mt < 4; ++mt) {
        int rowg = b * 49 + 16 * mt + c;
        rowg = min(rowg, MTOT - 1); // clamp: tail garbage is finite & masked
        const float* xr = x + (size_t)rowg * 128;
#pragma unroll
        for (int ks = 0; ks < 4; ++ks) {
            float4 lo = *(const float4*)(xr + 32 * ks + 8 * g);
            float4 hi = *(const float4*)(xr + 32 * ks + 8 * g + 4);
            half8 v;
            v[0] = (_Float16)lo.x; v[1] = (_Float16)lo.y;
            v[2] = (_Float16)lo.z; v[3] = (_Float16)lo.w;
            v[4] = (_Float16)hi.x; v[5] = (_Float16)hi.y;
            v[6] = (_Float16)hi.z; v[7] = (_Float16)hi.w;
            af[mt][ks] = v;
        }
    }

    // ---- qkv gemm: 6 w-tiles (q0,q1,k0,k1,v0,v1), bf double-buffered, all mt at once ----
    unsigned vlo[4][2], vhi[4][2]; // V in C-layout packs: [mt][dhalf]
    half8 bf0[4], bf1[4];
#pragma unroll
    for (int ks = 0; ks < 4; ++ks)
        bf0[ks] = *(const half8*)(w16 + (size_t)(0 * 128 + h * 32 + 0 * 16 + c) * 128 + 32 * ks + 8 * g);
#pragma unroll
    for (int jt = 0; jt < 6; ++jt) {
        const int sec = jt >> 1, dhalf = jt & 1;
        const int tb = sec * 128 + h * 32 + dhalf * 16;
        // prefetch next tile's weights
        if (jt < 5) {
            const int jn = jt + 1;
            const int tbn = (jn >> 1) * 128 + h * 32 + (jn & 1) * 16;
#pragma unroll
            for (int ks = 0; ks < 4; ++ks)
                bf1[ks] = *(const half8*)(w16 + (size_t)(tbn + c) * 128 + 32 * ks + 8 * g);
        }
        f32x4 acc[4];
#pragma unroll
        for (int mt = 0; mt < 4; ++mt) acc[mt] = (f32x4){0.f, 0.f, 0.f, 0.f};
#pragma unroll
        for (int ks = 0; ks < 4; ++ks)
#pragma unroll
            for (int mt = 0; mt < 4; ++mt)
                acc[mt] = __builtin_amdgcn_mfma_f32_16x16x32_f16(af[mt][ks], bf0[ks], acc[mt], 0, 0, 0);
        const float bv = qkv_b[tb + c];
#pragma unroll
        for (int mt = 0; mt < 4; ++mt) {
            if (sec == 2) {
                vlo[mt][dhalf] = packh2(acc[mt][0] + bv, acc[mt][1] + bv);
                vhi[mt][dhalf] = packh2(acc[mt][2] + bv, acc[mt][3] + bv);
            } else {
                unsigned short* dstS = (sec == 0) ? Qs : Ks;
                const float scl = (sec == 0) ? SCALE_Q : 1.0f;
                const int d = dhalf * 16 + c;
#pragma unroll
                for (int r = 0; r < 4; ++r) {
                    const int m = 16 * mt + 4 * g + r;
                    if (m < 49) dstS[m * 40 + d] = f2h((acc[mt][r] + bv) * scl);
                }
            }
        }
#pragma unroll
        for (int ks = 0; ks < 4; ++ks) bf0[ks] = bf1[ks];
    }

    // ---- hoist Q/K frags BEFORE Ps overlay clobbers Qs/Ks ----
    half8 qf[4], kf[4];
#pragma unroll
    for (int mt = 0; mt < 4; ++mt) qf[mt] = *(const half8*)(Qs + (16 * mt + c) * 40 + 8 * g);
#pragma unroll
    for (int nt = 0; nt < 4; ++nt) kf[nt] = *(const half8*)(Ks + (16 * nt + c) * 40 + 8 * g);

    // ---- QK^T (16 MFMAs, single pass) ----
    f32x4 s[4][4];
#pragma unroll
    for (int mt = 0; mt < 4; ++mt)
#pragma unroll
        for (int nt = 0; nt < 4; ++nt) {
            s[mt][nt] = (f32x4){0.f, 0.f, 0.f, 0.f};
            s[mt][nt] = __builtin_amdgcn_mfma_f32_16x16x32_f16(qf[mt], kf[nt], s[mt][nt], 0, 0, 0);
        }

    // ---- softmax, all 16 rows in flight: +cmb, exp (no max-sub), 16-lane sum, norm -> Ps ----
    const float* crow = cmb + (size_t)(((b & (NWIN - 1)) << 2) | h) * 2401;
#pragma unroll
    for (int mt = 0; mt < 4; ++mt) {
#pragma unroll
        for (int r = 0; r < 4; ++r) {
            const int m = 16 * mt + 4 * g + r;
            float sum = 0.f;
#pragma unroll
            for (int nt = 0; nt < 4; ++nt) {
                const int n = 16 * nt + c;
                float p = 0.f;
                if (m < 49 && n < 49) p = __expf(s[mt][nt][r] + crow[m * 49 + n]);
                s[mt][nt][r] = p;
                sum += p;
            }
#pragma unroll
            for (int sh = 1; sh < 16; sh <<= 1) sum += __shfl_xor(sum, sh, 64);
            const float iv = (m < 49) ? 1.0f / sum : 0.0f;
#pragma unroll
            for (int nt = 0; nt < 4; ++nt)
                Ps[m * 72 + 16 * nt + c] = f2h(s[mt][nt][r] * iv);
        }
    }

    // ---- PV: vf built from register V via shfl (no LDS for V) ----
    // target lane (c,g), k-slice ks, d-tile dt: vf[j] = v[32ks+8g+j][16dt+c];
    // source lane (c, 2*gl + j/4) holds it in tile mt'=2ks+gh, elem r=j%4.
    f32x4 o[4][2];
#pragma unroll
    for (int mt = 0; mt < 4; ++mt)
#pragma unroll
        for (int dt = 0; dt < 2; ++dt) o[mt][dt] = (f32x4){0.f, 0.f, 0.f, 0.f};

    const int s0 = c + 32 * gl, s1 = s0 + 16;
#pragma unroll
    for (int ks = 0; ks < 2; ++ks) {
        half8 vf[2];
#pragma unroll
        for (int dt = 0; dt < 2; ++dt) {
            unsigned a0 = __shfl(vlo[2 * ks][dt], s0), a1 = __shfl(vlo[2 * ks + 1][dt], s0);
            unsigned b0 = __shfl(vhi[2 * ks][dt], s0), b1 = __shfl(vhi[2 * ks + 1][dt], s0);
            unsigned c0 = __shfl(vlo[2 * ks][dt], s1), c1 = __shfl(vlo[2 * ks + 1][dt], s1);
            unsigned d0 = __shfl(vhi[2 * ks][dt], s1), d1 = __shfl(vhi[2 * ks + 1][dt], s1);
            uint4 vv;
            vv.x = gh ? a1 : a0; vv.y = gh ? b1 : b0;
            vv.z = gh ? c1 : c0; vv.w = gh ? d1 : d0;
            vf[dt] = __builtin_bit_cast(half8, vv);
        }
#pragma unroll
        for (int mt = 0; mt < 4; ++mt) {
            half8 pf = *(const half8*)(Ps + (16 * mt + c) * 72 + 8 * g + 32 * ks);
#pragma unroll
            for (int dt = 0; dt < 2; ++dt)
                o[mt][dt] = __builtin_amdgcn_mfma_f32_16x16x32_f16(pf, vf[dt], o[mt][dt], 0, 0, 0);
        }
    }

    // ---- store aout (b, n, h*32+d) fp16 (P pre-normalized) ----
    unsigned short* orow = aout + (size_t)b * NTOK * DIMC + h * HD;
#pragma unroll
    for (int mt = 0; mt < 4; ++mt) {
#pragma unroll
        for (int r = 0; r < 4; ++r) {
            const int m = 16 * mt + 4 * g + r;
            if (m < 49) {
#pragma unroll
                for (int dt = 0; dt < 2; ++dt)
                    orow[m * DIMC + 16 * dt + c] = f2h(o[mt][dt][r]);
            }
        }
    }
}

// ---------------- GEMM2: out = attn_out @ proj_w^T + proj_b (f32 out) — at HBM floor ----------------
__global__ __launch_bounds__(256) void proj_gemm_mfma(
    const unsigned short* __restrict__ a, const float* __restrict__ w,
    const float* __restrict__ bias, float* __restrict__ out)
{
    __shared__ unsigned short As[128 * LDP];
    __shared__ unsigned short Bs[128 * LDP];
    const int t = threadIdx.x, lane = t & 63, wid = t >> 6;
    const int c = lane & 15, g = lane >> 4;
    const int m0 = blockIdx.x * 128;

#pragma unroll
    for (int i = 0; i < 8; ++i) {
        int idx = i * 256 + t;
        int row = idx >> 4, c8 = (idx & 15) * 8;
        *(uint4*)&As[row * LDP + c8] = *(const uint4*)(a + (size_t)(m0 + row) * 128 + c8);
    }
#pragma unroll
    for (int i = 0; i < 8; ++i) {
        int idx = i * 256 + t;
        int row = idx >> 4, c8 = (idx & 15) * 8;
        const float* sb = w + (size_t)row * 128 + c8;
        float4 b0 = *(const float4*)sb, b1 = *(const float4*)(sb + 4);
        ushortv8 pb = { f2h(b0.x), f2h(b0.y), f2h(b0.z), f2h(b0.w),
                        f2h(b1.x), f2h(b1.y), f2h(b1.z), f2h(b1.w) };
        *(ushortv8*)&Bs[row * LDP + c8] = pb;
    }
    __syncthreads();

    const int wr = wid >> 1, wc = wid & 1;
    f32x4 acc[4][4];
#pragma unroll
    for (int mt = 0; mt < 4; ++mt)
#pragma unroll
        for (int nt = 0; nt < 4; ++nt) acc[mt][nt] = (f32x4){0.f, 0.f, 0.f, 0.f};

#pragma unroll
    for (int ks = 0; ks < 4; ++ks) {
        half8 af[4], bf[4];
#pragma unroll
        for (int mt = 0; mt < 4; ++mt)
            af[mt] = *(const half8*)&As[(64 * wr + 16 * mt + c) * LDP + 32 * ks + 8 * g];
#pragma unroll
        for (int nt = 0; nt < 4; ++nt)
            bf[nt] = *(const half8*)&Bs[(64 * wc + 16 * nt + c) * LDP + 32 * ks + 8 * g];
#pragma unroll
        for (int mt = 0; mt < 4; ++mt)
#pragma unroll
            for (int nt = 0; nt < 4; ++nt)
                acc[mt][nt] = __builtin_amdgcn_mfma_f32_16x16x32_f16(af[mt], bf[nt], acc[mt][nt], 0, 0, 0);
    }

#pragma unroll
    for (int nt = 0; nt < 4; ++nt) {
        const int col = 64 * wc + 16 * nt + c;
        const float bv = bias[col];
#pragma unroll
        for (int mt = 0; mt < 4; ++mt) {
#pragma unroll
            for (int r = 0; r < 4; ++r) {
                int m = m0 + 64 * wr + 16 * mt + 4 * g + r;
                out[(size_t)m * 128 + col] = acc[mt][nt][r] + bv;
            }
        }
    }
}

extern "C" void kernel_launch(void* const* d_in, const int* in_sizes, int n_in,
                              void* d_out, int out_size, void* d_ws, size_t ws_size,
                              hipStream_t stream) {
    const float* x      = (const float*)d_in[0];
    const float* mask   = (const float*)d_in[1];
    const float* qkv_w  = (const float*)d_in[2];
    const float* qkv_b  = (const float*)d_in[3];
    const float* proj_w = (const float*)d_in[4];
    const float* proj_b = (const float*)d_in[5];
    const float* rpb    = (const float*)d_in[6];
    const int*   rpi    = (const int*)d_in[7];
    float* out = (float*)d_out;

    unsigned short* ab  = (unsigned short*)d_ws;          // 25,690,112 u16 (49 MB)
    unsigned short* w16 = ab + (size_t)MTOT * DIMC;       // 49,152 u16
    float* cmb = (float*)(w16 + 49152);                   // 614,656 f32 (2.5 MB)

    prep_w16<<<dim3(192), 256, 0, stream>>>(qkv_w, w16);
    prep_cmb<<<dim3(2401), 256, 0, stream>>>(rpb, rpi, mask, cmb);
    attn_fused<<<dim3(B_WIN), 256, 0, stream>>>(x, w16, qkv_b, cmb, ab);
    proj_gemm_mfma<<<dim3(MTOT / 128), 256, 0, stream>>>(ab, proj_w, proj_b, out);
}

// Round 10
// 161.836 us; speedup vs baseline: 1.4601x; 1.0874x over previous
//
#include <hip/hip_runtime.h>

// Window attention, fused fp16-MFMA. Block = 1 window (4 waves = 4 heads), no barriers.
// prep_w16: qkv_w f32->fp16. prep_cmb: cmb[w][h][e] = rpb[rpi[e]*4+h] + mask[w][e].
// attn_fused: per wave: qkv gemm (A=x global+cvt, B=w16 global dbuf) -> Q,K wave-private
//   LDS; V in registers; QK^T -> exp (no max-sub) -> P unnormalized -> PV with ones-column
//   (row sums via MFMA, no cross-lane reduce) -> normalize at store -> aout fp16.
// proj_gemm_mfma: out = aout @ proj_w^T + proj_b (f32), at HBM floor.
#define B_WIN 4096
#define NTOK 49
#define DIMC 128
#define HEADS 4
#define HD 32
#define NWIN 64
#define MTOT (B_WIN * 49) /* 200704 */
#define SCALE_Q 0.17677669529663687f /* 32^-0.5 */

typedef _Float16 half8 __attribute__((ext_vector_type(8)));
typedef float f32x4 __attribute__((ext_vector_type(4)));
typedef unsigned short ushortv8 __attribute__((ext_vector_type(8)));

__device__ __forceinline__ unsigned short f2h(float f) {
    _Float16 h = (_Float16)f; // RNE
    return __builtin_bit_cast(unsigned short, h);
}
__device__ __forceinline__ unsigned packh2(float a, float b) {
    return (unsigned)f2h(a) | ((unsigned)f2h(b) << 16);
}

#define LDP 136 /* fp16 LDS row pitch for proj GEMM */

// ---------------- prep1: qkv_w f32 -> fp16 ----------------
__global__ __launch_bounds__(256) void prep_w16(
    const float* __restrict__ w, unsigned short* __restrict__ w16)
{
    int i = blockIdx.x * 256 + threadIdx.x;
    if (i < 384 * 128) w16[i] = f2h(w[i]);
}

// ---------------- prep2: combined bias+mask table cmb[w][h][e] ----------------
__global__ __launch_bounds__(256) void prep_cmb(
    const float* __restrict__ rpb, const int* __restrict__ rpi,
    const float* __restrict__ mask, float* __restrict__ cmb)
{
    int idx = blockIdx.x * 256 + threadIdx.x; // 64*4*2401 = 614656
    if (idx < NWIN * HEADS * 2401) {
        int e = idx % 2401;
        int wh = idx / 2401;
        int h = wh & 3, w = wh >> 2;
        cmb[idx] = rpb[rpi[e] * 4 + h] + mask[w * 2401 + e];
    }
}

// ---------------- fused qkv-gemm + attention ----------------
// Per-wave LDS 10240 B: Qs[64][40] | Ks[64][40]; Ps[64][72] (9216 B) overlays Qs+Ks.
// 4 waves x 10240 = 40960 B/block.
__global__ __launch_bounds__(256, 3) void attn_fused(
    const float* __restrict__ x, const unsigned short* __restrict__ w16,
    const float* __restrict__ qkv_b, const float* __restrict__ cmb,
    unsigned short* __restrict__ aout)
{
    __shared__ __align__(16) char smem[4 * 10240];
    const int t = threadIdx.x, wv = t >> 6, lane = t & 63;
    const int c = lane & 15, g = lane >> 4;
    const int gl = g & 1, gh = g >> 1;
    const int b = blockIdx.x, h = wv;

    unsigned short* Qs = (unsigned short*)(smem + wv * 10240); // [64][40]
    unsigned short* Ks = Qs + 64 * 40;                          // [64][40]
    unsigned short* Ps = Qs;                                    // [64][72] overlay

    // ---- x A-frags, f32 -> fp16 in-reg ----
    half8 af[4][4];
#pragma unroll
    for (int mt = 0; mt < 4; ++mt) {
        int rowg = b * 49 + 16 * mt + c;
        rowg = min(rowg, MTOT - 1); // clamp: tail garbage is finite & masked
        const float* xr = x + (size_t)rowg * 128;
#pragma unroll
        for (int ks = 0; ks < 4; ++ks) {
            float4 lo = *(const float4*)(xr + 32 * ks + 8 * g);
            float4 hi = *(const float4*)(xr + 32 * ks + 8 * g + 4);
            half8 v;
            v[0] = (_Float16)lo.x; v[1] = (_Float16)lo.y;
            v[2] = (_Float16)lo.z; v[3] = (_Float16)lo.w;
            v[4] = (_Float16)hi.x; v[5] = (_Float16)hi.y;
            v[6] = (_Float16)hi.z; v[7] = (_Float16)hi.w;
            af[mt][ks] = v;
        }
    }

    // ---- qkv gemm: 6 w-tiles (q0,q1,k0,k1,v0,v1), bf double-buffered ----
    unsigned vlo[4][2], vhi[4][2]; // V in C-layout packs: [mt][dhalf]
    half8 bf0[4], bf1[4];
#pragma unroll
    for (int ks = 0; ks < 4; ++ks)
        bf0[ks] = *(const half8*)(w16 + (size_t)(h * 32 + c) * 128 + 32 * ks + 8 * g);
#pragma unroll
    for (int jt = 0; jt < 6; ++jt) {
        const int sec = jt >> 1, dhalf = jt & 1;
        const int tb = sec * 128 + h * 32 + dhalf * 16;
        if (jt < 5) {
            const int jn = jt + 1;
            const int tbn = (jn >> 1) * 128 + h * 32 + (jn & 1) * 16;
#pragma unroll
            for (int ks = 0; ks < 4; ++ks)
                bf1[ks] = *(const half8*)(w16 + (size_t)(tbn + c) * 128 + 32 * ks + 8 * g);
        }
        f32x4 acc[4];
#pragma unroll
        for (int mt = 0; mt < 4; ++mt) acc[mt] = (f32x4){0.f, 0.f, 0.f, 0.f};
#pragma unroll
        for (int ks = 0; ks < 4; ++ks)
#pragma unroll
            for (int mt = 0; mt < 4; ++mt)
                acc[mt] = __builtin_amdgcn_mfma_f32_16x16x32_f16(af[mt][ks], bf0[ks], acc[mt], 0, 0, 0);
        const float bv = qkv_b[tb + c];
#pragma unroll
        for (int mt = 0; mt < 4; ++mt) {
            if (sec == 2) {
                vlo[mt][dhalf] = packh2(acc[mt][0] + bv, acc[mt][1] + bv);
                vhi[mt][dhalf] = packh2(acc[mt][2] + bv, acc[mt][3] + bv);
            } else {
                unsigned short* dstS = (sec == 0) ? Qs : Ks;
                const float scl = (sec == 0) ? SCALE_Q : 1.0f;
                const int d = dhalf * 16 + c;
#pragma unroll
                for (int r = 0; r < 4; ++r) {
                    const int m = 16 * mt + 4 * g + r;
                    if (m < 49) dstS[m * 40 + d] = f2h((acc[mt][r] + bv) * scl);
                }
            }
        }
#pragma unroll
        for (int ks = 0; ks < 4; ++ks) bf0[ks] = bf1[ks];
    }

    // ---- hoist Q/K frags BEFORE Ps overlay clobbers Qs/Ks ----
    half8 qf[4], kf[4];
#pragma unroll
    for (int mt = 0; mt < 4; ++mt) qf[mt] = *(const half8*)(Qs + (16 * mt + c) * 40 + 8 * g);
#pragma unroll
    for (int nt = 0; nt < 4; ++nt) kf[nt] = *(const half8*)(Ks + (16 * nt + c) * 40 + 8 * g);

    // ---- QK^T (16 MFMAs) ----
    f32x4 s[4][4];
#pragma unroll
    for (int mt = 0; mt < 4; ++mt)
#pragma unroll
        for (int nt = 0; nt < 4; ++nt) {
            s[mt][nt] = (f32x4){0.f, 0.f, 0.f, 0.f};
            s[mt][nt] = __builtin_amdgcn_mfma_f32_16x16x32_f16(qf[mt], kf[nt], s[mt][nt], 0, 0, 0);
        }

    // ---- exp (no max-sub, no row reduce): P unnormalized -> Ps ----
    // cmb loads batched per mt (unconditional safe-index) for memory-level parallelism.
    const float* crow = cmb + (size_t)(((b & (NWIN - 1)) << 2) | h) * 2401;
#pragma unroll
    for (int mt = 0; mt < 4; ++mt) {
        float cv[4][4];
#pragma unroll
        for (int nt = 0; nt < 4; ++nt)
#pragma unroll
            for (int r = 0; r < 4; ++r) {
                const int m = 16 * mt + 4 * g + r;
                const int n = 16 * nt + c;
                const int e = (m < 49 && n < 49) ? (m * 49 + n) : 0;
                cv[nt][r] = crow[e];
            }
#pragma unroll
        for (int nt = 0; nt < 4; ++nt)
#pragma unroll
            for (int r = 0; r < 4; ++r) {
                const int m = 16 * mt + 4 * g + r;
                const int n = 16 * nt + c;
                float p = (m < 49 && n < 49) ? __expf(s[mt][nt][r] + cv[nt][r]) : 0.f;
                Ps[m * 72 + 16 * nt + c] = f2h(p);
            }
    }

    // ---- PV with ones-column: o = P@V, osum = P@1 (row sums, same C-layout rows) ----
    f32x4 o[4][2], osum[4];
#pragma unroll
    for (int mt = 0; mt < 4; ++mt) {
        o[mt][0] = (f32x4){0.f, 0.f, 0.f, 0.f};
        o[mt][1] = (f32x4){0.f, 0.f, 0.f, 0.f};
        osum[mt] = (f32x4){0.f, 0.f, 0.f, 0.f};
    }
    const _Float16 one16 = (_Float16)1.0f;
    const half8 onesf = {one16, one16, one16, one16, one16, one16, one16, one16};

    const int s0 = c + 32 * gl, s1 = s0 + 16;
#pragma unroll
    for (int ks = 0; ks < 2; ++ks) {
        half8 vf[2];
#pragma unroll
        for (int dt = 0; dt < 2; ++dt) {
            unsigned a0 = __shfl(vlo[2 * ks][dt], s0), a1 = __shfl(vlo[2 * ks + 1][dt], s0);
            unsigned b0 = __shfl(vhi[2 * ks][dt], s0), b1 = __shfl(vhi[2 * ks + 1][dt], s0);
            unsigned c0 = __shfl(vlo[2 * ks][dt], s1), c1 = __shfl(vlo[2 * ks + 1][dt], s1);
            unsigned d0 = __shfl(vhi[2 * ks][dt], s1), d1 = __shfl(vhi[2 * ks + 1][dt], s1);
            uint4 vv;
            vv.x = gh ? a1 : a0; vv.y = gh ? b1 : b0;
            vv.z = gh ? c1 : c0; vv.w = gh ? d1 : d0;
            vf[dt] = __builtin_bit_cast(half8, vv);
        }
#pragma unroll
        for (int mt = 0; mt < 4; ++mt) {
            half8 pf = *(const half8*)(Ps + (16 * mt + c) * 72 + 8 * g + 32 * ks);
            o[mt][0] = __builtin_amdgcn_mfma_f32_16x16x32_f16(pf, vf[0], o[mt][0], 0, 0, 0);
            o[mt][1] = __builtin_amdgcn_mfma_f32_16x16x32_f16(pf, vf[1], o[mt][1], 0, 0, 0);
            osum[mt] = __builtin_amdgcn_mfma_f32_16x16x32_f16(pf, onesf, osum[mt], 0, 0, 0);
        }
    }

    // ---- normalize at store: aout (b, n, h*32+d) fp16 ----
    unsigned short* orow = aout + (size_t)b * NTOK * DIMC + h * HD;
#pragma unroll
    for (int mt = 0; mt < 4; ++mt) {
#pragma unroll
        for (int r = 0; r < 4; ++r) {
            const int m = 16 * mt + 4 * g + r;
            if (m < 49) {
                const float iv = 1.0f / osum[mt][r];
#pragma unroll
                for (int dt = 0; dt < 2; ++dt)
                    orow[m * DIMC + 16 * dt + c] = f2h(o[mt][dt][r] * iv);
            }
        }
    }
}

// ---------------- GEMM2: out = attn_out @ proj_w^T + proj_b (f32 out) — at HBM floor ----------------
__global__ __launch_bounds__(256) void proj_gemm_mfma(
    const unsigned short* __restrict__ a, const float* __restrict__ w,
    const float* __restrict__ bias, float* __restrict__ out)
{
    __shared__ unsigned short As[128 * LDP];
    __shared__ unsigned short Bs[128 * LDP];
    const int t = threadIdx.x, lane = t & 63, wid = t >> 6;
    const int c = lane & 15, g = lane >> 4;
    const int m0 = blockIdx.x * 128;

#pragma unroll
    for (int i = 0; i < 8; ++i) {
        int idx = i * 256 + t;
        int row = idx >> 4, c8 = (idx & 15) * 8;
        *(uint4*)&As[row * LDP + c8] = *(const uint4*)(a + (size_t)(m0 + row) * 128 + c8);
    }
#pragma unroll
    for (int i = 0; i < 8; ++i) {
        int idx = i * 256 + t;
        int row = idx >> 4, c8 = (idx & 15) * 8;
        const float* sb = w + (size_t)row * 128 + c8;
        float4 b0 = *(const float4*)sb, b1 = *(const float4*)(sb + 4);
        ushortv8 pb = { f2h(b0.x), f2h(b0.y), f2h(b0.z), f2h(b0.w),
                        f2h(b1.x), f2h(b1.y), f2h(b1.z), f2h(b1.w) };
        *(ushortv8*)&Bs[row * LDP + c8] = pb;
    }
    __syncthreads();

    const int wr = wid >> 1, wc = wid & 1;
    f32x4 acc[4][4];
#pragma unroll
    for (int mt = 0; mt < 4; ++mt)
#pragma unroll
        for (int nt = 0; nt < 4; ++nt) acc[mt][nt] = (f32x4){0.f, 0.f, 0.f, 0.f};

#pragma unroll
    for (int ks = 0; ks < 4; ++ks) {
        half8 af[4], bf[4];
#pragma unroll
        for (int mt = 0; mt < 4; ++mt)
            af[mt] = *(const half8*)&As[(64 * wr + 16 * mt + c) * LDP + 32 * ks + 8 * g];
#pragma unroll
        for (int nt = 0; nt < 4; ++nt)
            bf[nt] = *(const half8*)&Bs[(64 * wc + 16 * nt + c) * LDP + 32 * ks + 8 * g];
#pragma unroll
        for (int mt = 0; mt < 4; ++mt)
#pragma unroll
            for (int nt = 0; nt < 4; ++nt)
                acc[mt][nt] = __builtin_amdgcn_mfma_f32_16x16x32_f16(af[mt], bf[nt], acc[mt][nt], 0, 0, 0);
    }

#pragma unroll
    for (int nt = 0; nt < 4; ++nt) {
        const int col = 64 * wc + 16 * nt + c;
        const float bv = bias[col];
#pragma unroll
        for (int mt = 0; mt < 4; ++mt) {
#pragma unroll
            for (int r = 0; r < 4; ++r) {
                int m = m0 + 64 * wr + 16 * mt + 4 * g + r;
                out[(size_t)m * 128 + col] = acc[mt][nt][r] + bv;
            }
        }
    }
}

extern "C" void kernel_launch(void* const* d_in, const int* in_sizes, int n_in,
                              void* d_out, int out_size, void* d_ws, size_t ws_size,
                              hipStream_t stream) {
    const float* x      = (const float*)d_in[0];
    const float* mask   = (const float*)d_in[1];
    const float* qkv_w  = (const float*)d_in[2];
    const float* qkv_b  = (const float*)d_in[3];
    const float* proj_w = (const float*)d_in[4];
    const float* proj_b = (const float*)d_in[5];
    const float* rpb    = (const float*)d_in[6];
    const int*   rpi    = (const int*)d_in[7];
    float* out = (float*)d_out;

    unsigned short* ab  = (unsigned short*)d_ws;          // 25,690,112 u16 (49 MB)
    unsigned short* w16 = ab + (size_t)MTOT * DIMC;       // 49,152 u16
    float* cmb = (float*)(w16 + 49152);                   // 614,656 f32 (2.5 MB)

    prep_w16<<<dim3(192), 256, 0, stream>>>(qkv_w, w16);
    prep_cmb<<<dim3(2401), 256, 0, stream>>>(rpb, rpi, mask, cmb);
    attn_fused<<<dim3(B_WIN), 256, 0, stream>>>(x, w16, qkv_b, cmb, ab);
    proj_gemm_mfma<<<dim3(MTOT / 128), 256, 0, stream>>>(ab, proj_w, proj_b, out);
}

// Round 11
// 108.090 us; speedup vs baseline: 2.1861x; 1.4972x over previous
//
#include <hip/hip_runtime.h>

// Window attention, fused fp16-MFMA, fully-coalesced memory paths.
// prep_w2: qkv_w f32 -> fp16, permuted to MFMA B-frag order (1-seg loads).
// prep_cmb2: bias+mask folded, permuted to C-frag lane order (1-seg loads).
// attn_fused: block = 1 window (4 waves = 4 heads): coalesced x -> LDS fp16 (xs) ->
//   af frags hoisted -> qkv gemm -> Q,K wave-private LDS (overlay xs), V in regs ->
//   QK^T -> exp (no max-sub) -> P unnorm -> PV + ones-column rowsum -> aout fp16.
// proj_gemm_mfma: out = aout @ proj_w^T + proj_b (f32), at HBM floor.
#define B_WIN 4096
#define NTOK 49
#define DIMC 128
#define HEADS 4
#define HD 32
#define NWIN 64
#define MTOT (B_WIN * 49) /* 200704 */
#define SCALE_Q 0.17677669529663687f /* 32^-0.5 */

typedef _Float16 half8 __attribute__((ext_vector_type(8)));
typedef float f32x4 __attribute__((ext_vector_type(4)));
typedef unsigned short ushortv8 __attribute__((ext_vector_type(8)));

__device__ __forceinline__ unsigned short f2h(float f) {
    _Float16 h = (_Float16)f; // RNE
    return __builtin_bit_cast(unsigned short, h);
}
__device__ __forceinline__ unsigned packh2(float a, float b) {
    return (unsigned)f2h(a) | ((unsigned)f2h(b) << 16);
}

struct alignas(8) US4 { unsigned short x, y, z, w; };

#define LDP 136 /* fp16 LDS row pitch for proj GEMM */
#define XSP 136 /* xs pitch (u16): 272B/row -> 4-bank row step -> <=2-way on b128 */

// ---------------- prep1: qkv_w f32 -> fp16, B-frag-ordered ----------------
// w2[(((h*6+jt)*4+ks)*64 + lane)*8 + j] = w[(tb+c)*128 + 32ks+8g+j], tb=sec*128+h*32+dhalf*16
__global__ __launch_bounds__(256) void prep_w2(
    const float* __restrict__ w, unsigned short* __restrict__ w2)
{
    int id = blockIdx.x * 256 + threadIdx.x; // < 4*6*4*64 = 6144
    if (id >= 6144) return;
    int lane = id & 63, ks = (id >> 6) & 3, jt = (id >> 8) % 6, h = id / 1536;
    int c = lane & 15, g = lane >> 4;
    int sec = jt >> 1, dhalf = jt & 1;
    int tb = sec * 128 + h * 32 + dhalf * 16;
    const float* src = w + (size_t)(tb + c) * 128 + 32 * ks + 8 * g;
    ushortv8 p;
#pragma unroll
    for (int j = 0; j < 8; ++j) p[j] = f2h(src[j]);
    *(ushortv8*)(w2 + (size_t)id * 8) = p;
}

// ---------------- prep2: bias+mask, C-frag lane-ordered; pads = 0 ----------------
// cmb2[((w*4+h)*64 + mt*16+nt*4+r)*64 + lane] = rpb[rpi[e]*4+h] + mask[w][e], e=m*49+n
__global__ __launch_bounds__(256) void prep_cmb2(
    const float* __restrict__ rpb, const int* __restrict__ rpi,
    const float* __restrict__ mask, float* __restrict__ cmb2)
{
    int id = blockIdx.x * 256 + threadIdx.x; // < 64*4*64*64 = 1048576
    int lane = id & 63, idx = (id >> 6) & 63, wh = id >> 12;
    int h = wh & 3, w = wh >> 2;
    int mt = idx >> 4, nt = (idx >> 2) & 3, r = idx & 3;
    int c = lane & 15, g = lane >> 4;
    int m = 16 * mt + 4 * g + r, n = 16 * nt + c;
    float v = 0.f;
    if (m < 49 && n < 49) {
        int e = m * 49 + n;
        v = rpb[rpi[e] * 4 + h] + mask[w * 2401 + e];
    }
    cmb2[id] = v;
}

// ---------------- fused qkv-gemm + attention ----------------
// LDS 40960 B: 4 x per-wave {Qs[64][40] | Ks[64][40]} (Ps[64][72] overlays);
// xs[49][136] (13328 B) overlays the front and is dead before Qs/Ks writes.
__global__ __launch_bounds__(256, 3) void attn_fused(
    const float* __restrict__ x, const unsigned short* __restrict__ w2,
    const float* __restrict__ qkv_b, const float* __restrict__ cmb2,
    unsigned short* __restrict__ aout)
{
    __shared__ __align__(16) char smem[4 * 10240];
    const int t = threadIdx.x, wv = t >> 6, lane = t & 63;
    const int c = lane & 15, g = lane >> 4;
    const int gl = g & 1, gh = g >> 1;
    const int b = blockIdx.x, h = wv;

    unsigned short* xs = (unsigned short*)smem;                 // [49][XSP] overlay
    unsigned short* Qs = (unsigned short*)(smem + wv * 10240);  // [64][40]
    unsigned short* Ks = Qs + 64 * 40;                          // [64][40]
    unsigned short* Ps = Qs;                                    // [64][72] overlay

    // ---- stage window x: coalesced f32 loads -> fp16 xs ----
    {
        const float* xw = x + (size_t)b * (49 * 128);
#pragma unroll
        for (int it = 0; it < 7; ++it) {
            int idx = it * 256 + t; // 1568 float4 chunks (49*128/8 pairs of float4)
            if (idx < 1568) {
                int row = idx >> 5, c4 = (idx & 31) * 4;
                float4 v = *(const float4*)(xw + row * 128 + c4);
                US4 p; p.x = f2h(v.x); p.y = f2h(v.y); p.z = f2h(v.z); p.w = f2h(v.w);
                *(US4*)(xs + row * XSP + c4) = p;
            }
        }
    }
    __syncthreads(); // xs staged (cross-wave) before frag reads

    // ---- hoist all A-frags from xs (rows clamped to 48; garbage masked later) ----
    half8 af[4][4];
#pragma unroll
    for (int mt = 0; mt < 4; ++mt) {
        const int row = min(16 * mt + c, 48);
#pragma unroll
        for (int ks = 0; ks < 4; ++ks)
            af[mt][ks] = *(const half8*)(xs + row * XSP + 32 * ks + 8 * g);
    }
    __syncthreads(); // all waves done reading xs before Qs/Ks overlay writes

    // ---- qkv gemm: 6 w-tiles (q0,q1,k0,k1,v0,v1), coalesced bf (dbuf) ----
    unsigned vlo[4][2], vhi[4][2]; // V in C-layout packs: [mt][dhalf]
    const unsigned short* wbase = w2 + (size_t)h * 12288; // 6*4*64*8
    half8 bf0[4], bf1[4];
#pragma unroll
    for (int ks = 0; ks < 4; ++ks)
        bf0[ks] = *(const half8*)(wbase + ((0 * 4 + ks) * 64 + lane) * 8);
#pragma unroll
    for (int jt = 0; jt < 6; ++jt) {
        const int sec = jt >> 1, dhalf = jt & 1;
        const int tb = sec * 128 + h * 32 + dhalf * 16;
        if (jt < 5) {
#pragma unroll
            for (int ks = 0; ks < 4; ++ks)
                bf1[ks] = *(const half8*)(wbase + (((jt + 1) * 4 + ks) * 64 + lane) * 8);
        }
        f32x4 acc[4];
#pragma unroll
        for (int mt = 0; mt < 4; ++mt) acc[mt] = (f32x4){0.f, 0.f, 0.f, 0.f};
#pragma unroll
        for (int ks = 0; ks < 4; ++ks)
#pragma unroll
            for (int mt = 0; mt < 4; ++mt)
                acc[mt] = __builtin_amdgcn_mfma_f32_16x16x32_f16(af[mt][ks], bf0[ks], acc[mt], 0, 0, 0);
        const float bv = qkv_b[tb + c];
#pragma unroll
        for (int mt = 0; mt < 4; ++mt) {
            if (sec == 2) {
                vlo[mt][dhalf] = packh2(acc[mt][0] + bv, acc[mt][1] + bv);
                vhi[mt][dhalf] = packh2(acc[mt][2] + bv, acc[mt][3] + bv);
            } else {
                unsigned short* dstS = (sec == 0) ? Qs : Ks;
                const float scl = (sec == 0) ? SCALE_Q : 1.0f;
                const int d = dhalf * 16 + c;
#pragma unroll
                for (int r = 0; r < 4; ++r) {
                    const int m = 16 * mt + 4 * g + r;
                    if (m < 49) dstS[m * 40 + d] = f2h((acc[mt][r] + bv) * scl);
                }
            }
        }
#pragma unroll
        for (int ks = 0; ks < 4; ++ks) bf0[ks] = bf1[ks];
    }

    // ---- hoist Q/K frags BEFORE Ps overlay clobbers Qs/Ks (wave-private, in-order) ----
    half8 qf[4], kf[4];
#pragma unroll
    for (int mt = 0; mt < 4; ++mt) qf[mt] = *(const half8*)(Qs + (16 * mt + c) * 40 + 8 * g);
#pragma unroll
    for (int nt = 0; nt < 4; ++nt) kf[nt] = *(const half8*)(Ks + (16 * nt + c) * 40 + 8 * g);

    // ---- QK^T (16 MFMAs) ----
    f32x4 s[4][4];
#pragma unroll
    for (int mt = 0; mt < 4; ++mt)
#pragma unroll
        for (int nt = 0; nt < 4; ++nt) {
            s[mt][nt] = (f32x4){0.f, 0.f, 0.f, 0.f};
            s[mt][nt] = __builtin_amdgcn_mfma_f32_16x16x32_f16(qf[mt], kf[nt], s[mt][nt], 0, 0, 0);
        }

    // ---- exp (no max-sub): coalesced cmb2 loads, P unnormalized -> Ps ----
    const float* cbase = cmb2 + (size_t)(((b & (NWIN - 1)) << 2) | h) * 4096;
#pragma unroll
    for (int mt = 0; mt < 4; ++mt) {
        float cv[4][4];
#pragma unroll
        for (int nt = 0; nt < 4; ++nt)
#pragma unroll
            for (int r = 0; r < 4; ++r)
                cv[nt][r] = cbase[(mt * 16 + nt * 4 + r) * 64 + lane];
#pragma unroll
        for (int nt = 0; nt < 4; ++nt)
#pragma unroll
            for (int r = 0; r < 4; ++r) {
                const int m = 16 * mt + 4 * g + r;
                const int n = 16 * nt + c;
                float p = (m < 49 && n < 49) ? __expf(s[mt][nt][r] + cv[nt][r]) : 0.f;
                Ps[m * 72 + 16 * nt + c] = f2h(p);
            }
    }

    // ---- PV with ones-column: o = P@V, osum = P@1 ----
    f32x4 o[4][2], osum[4];
#pragma unroll
    for (int mt = 0; mt < 4; ++mt) {
        o[mt][0] = (f32x4){0.f, 0.f, 0.f, 0.f};
        o[mt][1] = (f32x4){0.f, 0.f, 0.f, 0.f};
        osum[mt] = (f32x4){0.f, 0.f, 0.f, 0.f};
    }
    const _Float16 one16 = (_Float16)1.0f;
    const half8 onesf = {one16, one16, one16, one16, one16, one16, one16, one16};

    const int s0 = c + 32 * gl, s1 = s0 + 16;
#pragma unroll
    for (int ks = 0; ks < 2; ++ks) {
        half8 vf[2];
#pragma unroll
        for (int dt = 0; dt < 2; ++dt) {
            unsigned a0 = __shfl(vlo[2 * ks][dt], s0), a1 = __shfl(vlo[2 * ks + 1][dt], s0);
            unsigned b0 = __shfl(vhi[2 * ks][dt], s0), b1 = __shfl(vhi[2 * ks + 1][dt], s0);
            unsigned c0 = __shfl(vlo[2 * ks][dt], s1), c1 = __shfl(vlo[2 * ks + 1][dt], s1);
            unsigned d0 = __shfl(vhi[2 * ks][dt], s1), d1 = __shfl(vhi[2 * ks + 1][dt], s1);
            uint4 vv;
            vv.x = gh ? a1 : a0; vv.y = gh ? b1 : b0;
            vv.z = gh ? c1 : c0; vv.w = gh ? d1 : d0;
            vf[dt] = __builtin_bit_cast(half8, vv);
        }
#pragma unroll
        for (int mt = 0; mt < 4; ++mt) {
            half8 pf = *(const half8*)(Ps + (16 * mt + c) * 72 + 8 * g + 32 * ks);
            o[mt][0] = __builtin_amdgcn_mfma_f32_16x16x32_f16(pf, vf[0], o[mt][0], 0, 0, 0);
            o[mt][1] = __builtin_amdgcn_mfma_f32_16x16x32_f16(pf, vf[1], o[mt][1], 0, 0, 0);
            osum[mt] = __builtin_amdgcn_mfma_f32_16x16x32_f16(pf, onesf, osum[mt], 0, 0, 0);
        }
    }

    // ---- normalize at store: aout (b, n, h*32+d) fp16 ----
    unsigned short* orow = aout + (size_t)b * NTOK * DIMC + h * HD;
#pragma unroll
    for (int mt = 0; mt < 4; ++mt) {
#pragma unroll
        for (int r = 0; r < 4; ++r) {
            const int m = 16 * mt + 4 * g + r;
            if (m < 49) {
                const float iv = 1.0f / osum[mt][r];
#pragma unroll
                for (int dt = 0; dt < 2; ++dt)
                    orow[m * DIMC + 16 * dt + c] = f2h(o[mt][dt][r] * iv);
            }
        }
    }
}

// ---------------- GEMM2: out = attn_out @ proj_w^T + proj_b (f32 out) — at HBM floor ----------------
__global__ __launch_bounds__(256) void proj_gemm_mfma(
    const unsigned short* __restrict__ a, const float* __restrict__ w,
    const float* __restrict__ bias, float* __restrict__ out)
{
    __shared__ unsigned short As[128 * LDP];
    __shared__ unsigned short Bs[128 * LDP];
    const int t = threadIdx.x, lane = t & 63, wid = t >> 6;
    const int c = lane & 15, g = lane >> 4;
    const int m0 = blockIdx.x * 128;

#pragma unroll
    for (int i = 0; i < 8; ++i) {
        int idx = i * 256 + t;
        int row = idx >> 4, c8 = (idx & 15) * 8;
        *(uint4*)&As[row * LDP + c8] = *(const uint4*)(a + (size_t)(m0 + row) * 128 + c8);
    }
#pragma unroll
    for (int i = 0; i < 8; ++i) {
        int idx = i * 256 + t;
        int row = idx >> 4, c8 = (idx & 15) * 8;
        const float* sb = w + (size_t)row * 128 + c8;
        float4 b0 = *(const float4*)sb, b1 = *(const float4*)(sb + 4);
        ushortv8 pb = { f2h(b0.x), f2h(b0.y), f2h(b0.z), f2h(b0.w),
                        f2h(b1.x), f2h(b1.y), f2h(b1.z), f2h(b1.w) };
        *(ushortv8*)&Bs[row * LDP + c8] = pb;
    }
    __syncthreads();

    const int wr = wid >> 1, wc = wid & 1;
    f32x4 acc[4][4];
#pragma unroll
    for (int mt = 0; mt < 4; ++mt)
#pragma unroll
        for (int nt = 0; nt < 4; ++nt) acc[mt][nt] = (f32x4){0.f, 0.f, 0.f, 0.f};

#pragma unroll
    for (int ks = 0; ks < 4; ++ks) {
        half8 af[4], bf[4];
#pragma unroll
        for (int mt = 0; mt < 4; ++mt)
            af[mt] = *(const half8*)&As[(64 * wr + 16 * mt + c) * LDP + 32 * ks + 8 * g];
#pragma unroll
        for (int nt = 0; nt < 4; ++nt)
            bf[nt] = *(const half8*)&Bs[(64 * wc + 16 * nt + c) * LDP + 32 * ks + 8 * g];
#pragma unroll
        for (int mt = 0; mt < 4; ++mt)
#pragma unroll
            for (int nt = 0; nt < 4; ++nt)
                acc[mt][nt] = __builtin_amdgcn_mfma_f32_16x16x32_f16(af[mt], bf[nt], acc[mt][nt], 0, 0, 0);
    }

#pragma unroll
    for (int nt = 0; nt < 4; ++nt) {
        const int col = 64 * wc + 16 * nt + c;
        const float bv = bias[col];
#pragma unroll
        for (int mt = 0; mt < 4; ++mt) {
#pragma unroll
            for (int r = 0; r < 4; ++r) {
                int m = m0 + 64 * wr + 16 * mt + 4 * g + r;
                out[(size_t)m * 128 + col] = acc[mt][nt][r] + bv;
            }
        }
    }
}

extern "C" void kernel_launch(void* const* d_in, const int* in_sizes, int n_in,
                              void* d_out, int out_size, void* d_ws, size_t ws_size,
                              hipStream_t stream) {
    const float* x      = (const float*)d_in[0];
    const float* mask   = (const float*)d_in[1];
    const float* qkv_w  = (const float*)d_in[2];
    const float* qkv_b  = (const float*)d_in[3];
    const float* proj_w = (const float*)d_in[4];
    const float* proj_b = (const float*)d_in[5];
    const float* rpb    = (const float*)d_in[6];
    const int*   rpi    = (const int*)d_in[7];
    float* out = (float*)d_out;

    unsigned short* ab = (unsigned short*)d_ws;           // 25,690,112 u16 (49 MB)
    unsigned short* w2 = ab + (size_t)MTOT * DIMC;        // 49,152 u16 (96 KB)
    float* cmb2 = (float*)(w2 + 49152);                   // 1,048,576 f32 (4 MB)

    prep_w2<<<dim3(24), 256, 0, stream>>>(qkv_w, w2);
    prep_cmb2<<<dim3(4096), 256, 0, stream>>>(rpb, rpi, mask, cmb2);
    attn_fused<<<dim3(B_WIN), 256, 0, stream>>>(x, w2, qkv_b, cmb2, ab);
    proj_gemm_mfma<<<dim3(MTOT / 128), 256, 0, stream>>>(ab, proj_w, proj_b, out);
}